// Round 8
// baseline (117.438 us; speedup 1.0000x reference)
//
#include <hip/hip_runtime.h>
#include <hip/hip_bf16.h>

typedef __attribute__((ext_vector_type(4))) float f32x4;
typedef __attribute__((ext_vector_type(8))) short short8v;
typedef __attribute__((ext_vector_type(8))) unsigned short ushort8v;
typedef __attribute__((ext_vector_type(4))) unsigned short ushort4v;

#define T_ROWS 16384
#define H_DIM  4096
#define E_NUM  64
#define TOPK   8
#define MROWS  16               // rows per block
#define KC     64               // k-chunk
#define NCH    (H_DIM / KC)     // 64 chunks
#define WIMG   16384            // bytes per W chunk image (hi+lo planes)

__device__ __forceinline__ unsigned short f2bf(float f) {
    unsigned int u = __float_as_uint(f);
    unsigned int r = (u + 0x7fffu + ((u >> 16) & 1u)) >> 16;  // RNE
    return (unsigned short)r;
}
__device__ __forceinline__ float bf2f(unsigned short h) {
    return __uint_as_float(((unsigned int)h) << 16);
}
// swizzled byte offset inside a [rows][128B] tile (row stride 128 B)
__device__ __forceinline__ int swz64(int row, int bytecol) {
    return row * 128 + (bytecol ^ ((row & 7) << 4));
}
__device__ __forceinline__ void gload_lds16(const void* g, void* l) {
    __builtin_amdgcn_global_load_lds(
        (const __attribute__((address_space(1))) unsigned int*)g,
        (__attribute__((address_space(3))) unsigned int*)l, 16, 0, 0);
}

// ---- prep: per-chunk swizzled LDS images of W (bf16 hi/lo) in d_ws ----
// for ch in [0,64): 16KB = [plane hi|lo 8KB][row 0..63][128B swizzled]
__global__ __launch_bounds__(256) void prep_w(
    const float* __restrict__ W, unsigned short* __restrict__ WS)
{
    const int g     = blockIdx.x * 256 + threadIdx.x;   // one 16B group
    const int byteo = g * 16;
    const int ch    = byteo >> 14;
    const int rem   = byteo & 16383;
    const int plane = rem >> 13;
    const int rb2   = rem & 8191;
    const int row   = rb2 >> 7;
    const int sb    = rb2 & 127;
    const int bc    = sb ^ ((row & 7) << 4);
    const float* src = W + (size_t)row * H_DIM + ch * KC + (bc >> 1);
    ushort8v o;
#pragma unroll
    for (int j = 0; j < 8; ++j) {
        const float f = src[j];
        const unsigned short hb = f2bf(f);
        o[j] = (plane == 0) ? hb : f2bf(f - bf2f(hb));
    }
    *(ushort8v*)((char*)WS + byteo) = o;
}

// ---- main: 256 thr = 4 waves; wave w = 16 rows x experts [w*16, w*16+16) ----
__global__ __launch_bounds__(256, 4) void router_main(
    const float* __restrict__ X, const unsigned short* __restrict__ WS,
    const int* __restrict__ ids, int nids, float* __restrict__ out)
{
    const int tid  = threadIdx.x;
    const int lane = tid & 63;
    const int w    = tid >> 6;        // 0..3 = expert quarter
    const int rb   = blockIdx.x * MROWS;
    const int fr   = lane & 15;
    const int fq   = lane >> 4;

    __shared__ unsigned short XB[2][2][MROWS * KC];   // [buf][plane] 2 KB each = 8 KB
    __shared__ unsigned short WB[2][WIMG / 2];        // 2 x 16 KB dbuf W images

    const int srow = tid >> 4;               // 0..15
    const int scf  = (tid & 15) * 4;         // f32 col
    const float* xg  = X + (size_t)(rb + srow) * H_DIM + scf;
    const char*  wsg = (const char*)WS;

    f32x4 acc = {0.f, 0.f, 0.f, 0.f};

    // ---- prologue: W chunk0 DMA, X chunk0 load + split ----
    {
        char* wd = (char*)&WB[0][0];
#pragma unroll
        for (int i = 0; i < 4; ++i) {
            const int off = (w * 4 + i) * 1024;
            gload_lds16(wsg + off + lane * 16, wd + off);
        }
    }
    float4 px = *(const float4*)(xg);
    ushort4v hv, lv;
    {
        float v[4] = {px.x, px.y, px.z, px.w};
#pragma unroll
        for (int j = 0; j < 4; ++j) {
            const unsigned short hb = f2bf(v[j]);
            hv[j] = hb;
            lv[j] = f2bf(v[j] - bf2f(hb));
        }
    }
    int cur = 0;

    for (int ch = 0; ch < NCH; ++ch) {
        // ---- stage this chunk's X split (two b64 writes) ----
        *(ushort4v*)((char*)&XB[cur][0][0] + swz64(srow, scf * 2)) = hv;
        *(ushort4v*)((char*)&XB[cur][1][0] + swz64(srow, scf * 2)) = lv;
        __syncthreads();   // drains W DMA (cur) + X writes; [cur] tiles ready
        // ---- issue next chunk's W DMA + X register load ----
        if (ch + 1 < NCH) {
            const char* wsn = wsg + (size_t)(ch + 1) * WIMG;
            char* wd = (char*)&WB[cur ^ 1][0];
#pragma unroll
            for (int i = 0; i < 4; ++i) {
                const int off = (w * 4 + i) * 1024;
                gload_lds16(wsn + off + lane * 16, wd + off);
            }
            px = *(const float4*)(xg + (ch + 1) * KC);
        }
        // ---- compute: 2 k-steps x 3 MFMA (split-bf16), same order as r6 ----
        const char* xh = (const char*)&XB[cur][0][0];
        const char* xl = (const char*)&XB[cur][1][0];
        const char* wb = (const char*)&WB[cur][0];
#pragma unroll
        for (int ks = 0; ks < KC / 32; ++ks) {
            const int bc = ks * 64 + fq * 16;
            short8v ah = *(const short8v*)(xh + swz64(fr, bc));
            short8v al = *(const short8v*)(xl + swz64(fr, bc));
            short8v bh = *(const short8v*)(wb + swz64(w * 16 + fr, bc));
            short8v bl = *(const short8v*)(wb + 8192 + swz64(w * 16 + fr, bc));
            acc = __builtin_amdgcn_mfma_f32_16x16x32_bf16(ah, bh, acc, 0, 0, 0);
            acc = __builtin_amdgcn_mfma_f32_16x16x32_bf16(ah, bl, acc, 0, 0, 0);
            acc = __builtin_amdgcn_mfma_f32_16x16x32_bf16(al, bh, acc, 0, 0, 0);
        }
        // ---- split next chunk's X (VALU; overlaps MFMA pipe) ----
        if (ch + 1 < NCH) {
            float v[4] = {px.x, px.y, px.z, px.w};
#pragma unroll
            for (int j = 0; j < 4; ++j) {
                const unsigned short hb = f2bf(v[j]);
                hv[j] = hb;
                lv[j] = f2bf(v[j] - bf2f(hb));
            }
        }
        cur ^= 1;
    }

    // ---- logits scoreboard in LDS (reuse W buffer), then epilogue ----
    __syncthreads();                       // all compute done
    float* sm = (float*)&WB[0][0];         // [16][68] = 4.3 KB << 32 KB
#pragma unroll
    for (int j = 0; j < 4; ++j) {
        const int row_l = fq * 4 + j;
        sm[row_l * 68 + w * 16 + fr] = acc[j];
    }
    __syncthreads();
    if (w != 0) return;                    // no barriers after this point

    // allowed-expert bitmask (uniform; scalar-cached)
    unsigned long long mbits = 0;
    for (int t = 0; t < nids; ++t) {
        const int e = ids[t];
        if (e >= 0 && e < E_NUM) mbits |= (1ull << e);
    }

    float* o_log = out;
    float* o_rw  = out + (size_t)T_ROWS * E_NUM;
    float* o_se  = o_rw + (size_t)T_ROWS * TOPK;

#pragma unroll
    for (int j = 0; j < 4; ++j) {
        const int row_l = fq * 4 + j;
        const int grow  = rb + row_l;
        float a0 = sm[row_l * 68 +  0 + fr];
        float a1 = sm[row_l * 68 + 16 + fr];
        float a2 = sm[row_l * 68 + 32 + fr];
        float a3 = sm[row_l * 68 + 48 + fr];
        float mv0 = ((mbits >> ( 0 + fr)) & 1) ? a0 : -10000.0f;
        float mv1 = ((mbits >> (16 + fr)) & 1) ? a1 : -10000.0f;
        float mv2 = ((mbits >> (32 + fr)) & 1) ? a2 : -10000.0f;
        float mv3 = ((mbits >> (48 + fr)) & 1) ? a3 : -10000.0f;
        o_log[(size_t)grow * 64 +  0 + fr] = mv0;
        o_log[(size_t)grow * 64 + 16 + fr] = mv1;
        o_log[(size_t)grow * 64 + 32 + fr] = mv2;
        o_log[(size_t)grow * 64 + 48 + fr] = mv3;

        float m = fmaxf(fmaxf(mv0, mv1), fmaxf(mv2, mv3));
#pragma unroll
        for (int off = 1; off < 16; off <<= 1) m = fmaxf(m, __shfl_xor(m, off));

        float tsum = 0.f, myv = 0.f;
        int   mye  = 0;
#pragma unroll
        for (int t = 0; t < TOPK; ++t) {
            float bv = mv0; int be = fr;
            if (mv1 > bv) { bv = mv1; be = 16 + fr; }
            if (mv2 > bv) { bv = mv2; be = 32 + fr; }
            if (mv3 > bv) { bv = mv3; be = 48 + fr; }
#pragma unroll
            for (int off = 1; off < 16; off <<= 1) {
                float ov = __shfl_xor(bv, off);
                int   oe = __shfl_xor(be, off);
                if (ov > bv || (ov == bv && oe < be)) { bv = ov; be = oe; }
            }
            const float pv = expf(bv - m);
            tsum += pv;
            if (fr == t) { myv = pv; mye = be; }
            if ((be & 15) == fr) {       // owner lane excludes winner
                const int bn = be >> 4;
                if      (bn == 0) mv0 = -3.4e38f;
                else if (bn == 1) mv1 = -3.4e38f;
                else if (bn == 2) mv2 = -3.4e38f;
                else              mv3 = -3.4e38f;
            }
        }
        if (fr < TOPK) {
            o_rw[(size_t)grow * TOPK + fr] = myv / tsum;
            o_se[(size_t)grow * TOPK + fr] = (float)mye;
        }
    }
}

extern "C" void kernel_launch(void* const* d_in, const int* in_sizes, int n_in,
                              void* d_out, int out_size, void* d_ws, size_t ws_size,
                              hipStream_t stream) {
    const float* X   = (const float*)d_in[0];
    const float* W   = (const float*)d_in[1];
    const int*   ids = (const int*)d_in[2];
    const int    nids = in_sizes[2];
    float* out = (float*)d_out;

    unsigned short* WS = (unsigned short*)d_ws;   // 1 MB swizzled W image

    hipLaunchKernelGGL(prep_w, dim3(NCH * WIMG / 16 / 256), dim3(256), 0, stream, W, WS);
    hipLaunchKernelGGL(router_main, dim3(T_ROWS / MROWS), dim3(256), 0, stream,
                       X, WS, ids, nids, out);
}

// Round 9
// 105.041 us; speedup vs baseline: 1.1180x; 1.1180x over previous
//
#include <hip/hip_runtime.h>
#include <hip/hip_bf16.h>

typedef __attribute__((ext_vector_type(4))) float f32x4;
typedef __attribute__((ext_vector_type(8))) short short8v;
typedef __attribute__((ext_vector_type(8))) unsigned short ushort8v;

#define T_ROWS 16384
#define H_DIM  4096
#define E_NUM  64
#define TOPK   8
#define MROWS  32               // rows per block
#define KC     64               // k-chunk
#define NCH    (H_DIM / KC)     // 64 chunks
#define WIMG   16384            // bytes per W chunk image (hi+lo planes)

__device__ __forceinline__ unsigned short f2bf(float f) {
    unsigned int u = __float_as_uint(f);
    unsigned int r = (u + 0x7fffu + ((u >> 16) & 1u)) >> 16;  // RNE
    return (unsigned short)r;
}
__device__ __forceinline__ float bf2f(unsigned short h) {
    return __uint_as_float(((unsigned int)h) << 16);
}
__device__ __forceinline__ void gload_lds16(const void* g, void* l) {
    __builtin_amdgcn_global_load_lds(
        (const __attribute__((address_space(1))) unsigned int*)g,
        (__attribute__((address_space(3))) unsigned int*)l, 16, 0, 0);
}

// ---- prep: per-chunk swizzled LDS images of W (bf16 hi/lo) in d_ws ----
// for ch in [0,64): 16KB = [plane hi|lo 8KB][row 0..63][128B swizzled]
__global__ __launch_bounds__(256) void prep_w(
    const float* __restrict__ W, unsigned short* __restrict__ WS)
{
    const int g     = blockIdx.x * 256 + threadIdx.x;   // one 16B group
    const int byteo = g * 16;
    const int ch    = byteo >> 14;
    const int rem   = byteo & 16383;
    const int plane = rem >> 13;
    const int rb2   = rem & 8191;
    const int row   = rb2 >> 7;
    const int sb    = rb2 & 127;
    const int bc    = sb ^ ((row & 7) << 4);
    const float* src = W + (size_t)row * H_DIM + ch * KC + (bc >> 1);
    ushort8v o;
#pragma unroll
    for (int j = 0; j < 8; ++j) {
        const float f = src[j];
        const unsigned short hb = f2bf(f);
        o[j] = (plane == 0) ? hb : f2bf(f - bf2f(hb));
    }
    *(ushort8v*)((char*)WS + byteo) = o;
}

// ---- main: 256 thr = 4 waves; wave (rg=w&1, cg=w>>1) = 16 rows x 32 experts ----
__global__ __launch_bounds__(256, 3) void router_main(
    const float* __restrict__ X, const unsigned short* __restrict__ WS,
    const int* __restrict__ ids, int nids, float* __restrict__ out)
{
    const int tid  = threadIdx.x;
    const int lane = tid & 63;
    const int w    = tid >> 6;        // 0..3
    const int rg   = w & 1;
    const int cg   = w >> 1;
    const int rb   = blockIdx.x * MROWS;
    const int fr   = lane & 15;
    const int fq   = lane >> 4;

    __shared__ float          XF[2][MROWS * KC];   // 2 x 8 KB, X f32 (src-xor-swizzled)
    __shared__ unsigned short WB[2][WIMG / 2];     // 2 x 16 KB, W images

    const char* wsg = (const char*)WS;

    f32x4 accT0 = {0.f, 0.f, 0.f, 0.f};
    f32x4 accT1 = accT0;

    // stage chunk ch into buffer b: exactly 6 global_load_lds per thread
    auto stage = [&](int ch, int b) {
        const char* wsn = wsg + (size_t)ch * WIMG;
        char* wd = (char*)&WB[b][0];
#pragma unroll
        for (int p = 0; p < 4; ++p) {
            const int off = p * 4096 + w * 1024;
            gload_lds16(wsn + off + lane * 16, wd + off);
        }
        char* xd = (char*)&XF[b][0];
#pragma unroll
        for (int p = 0; p < 2; ++p) {
            const int base = p * 4096 + w * 1024;           // wave-uniform dest
            const int row  = (base >> 8) + (lane >> 4);     // 0..31
            const int gc   = (lane & 15) ^ (row & 7);       // src chunk (xor-swizzle)
            gload_lds16(X + (size_t)(rb + row) * H_DIM + ch * KC + gc * 4,
                        xd + base);
        }
    };

    // ---- prologue: 2 chunks in flight ----
    stage(0, 0);
    stage(1, 1);
    int cur = 0;

    for (int ch = 0; ch < NCH; ++ch) {
        if (ch < NCH - 1) { asm volatile("s_waitcnt vmcnt(6)" ::: "memory"); }
        else              { asm volatile("s_waitcnt vmcnt(0)" ::: "memory"); }
        __builtin_amdgcn_sched_barrier(0);
        __builtin_amdgcn_s_barrier();          // buf[cur] ready for all waves
        __builtin_amdgcn_sched_barrier(0);

        const char* xb = (const char*)&XF[cur][0];
        const char* wb = (const char*)&WB[cur][0];
#pragma unroll
        for (int ks = 0; ks < KC / 32; ++ks) {
            const int arow = rg * 16 + fr;
            const int ab   = arow * 256 + ((ks * 128 + fq * 32) ^ ((arow & 7) << 4));
            const float4 a0 = *(const float4*)(xb + ab);
            const float4 a1 = *(const float4*)(xb + (ab ^ 16));
            float v[8] = {a0.x, a0.y, a0.z, a0.w, a1.x, a1.y, a1.z, a1.w};
            short8v ah, al;
#pragma unroll
            for (int j = 0; j < 8; ++j) {
                const unsigned short hb = f2bf(v[j]);
                ah[j] = (short)hb;
                al[j] = (short)f2bf(v[j] - bf2f(hb));
            }
            {
                const int brow = cg * 32 + fr;
                const int bb   = brow * 128 + ((ks * 64 + fq * 16) ^ ((brow & 7) << 4));
                short8v bh = *(const short8v*)(wb + bb);
                short8v bl = *(const short8v*)(wb + 8192 + bb);
                accT0 = __builtin_amdgcn_mfma_f32_16x16x32_bf16(ah, bh, accT0, 0, 0, 0);
                accT0 = __builtin_amdgcn_mfma_f32_16x16x32_bf16(ah, bl, accT0, 0, 0, 0);
                accT0 = __builtin_amdgcn_mfma_f32_16x16x32_bf16(al, bh, accT0, 0, 0, 0);
            }
            {
                const int brow = cg * 32 + 16 + fr;
                const int bb   = brow * 128 + ((ks * 64 + fq * 16) ^ ((brow & 7) << 4));
                short8v bh = *(const short8v*)(wb + bb);
                short8v bl = *(const short8v*)(wb + 8192 + bb);
                accT1 = __builtin_amdgcn_mfma_f32_16x16x32_bf16(ah, bh, accT1, 0, 0, 0);
                accT1 = __builtin_amdgcn_mfma_f32_16x16x32_bf16(ah, bl, accT1, 0, 0, 0);
                accT1 = __builtin_amdgcn_mfma_f32_16x16x32_bf16(al, bh, accT1, 0, 0, 0);
            }
        }

        asm volatile("s_waitcnt lgkmcnt(0)" ::: "memory");
        __builtin_amdgcn_sched_barrier(0);
        __builtin_amdgcn_s_barrier();          // all waves done reading buf[cur]
        __builtin_amdgcn_sched_barrier(0);
        if (ch + 2 < NCH) stage(ch + 2, cur);  // overwrite the just-freed buffer
        cur ^= 1;
    }

    // ---- logits scoreboard in LDS (reuse W buffers), then epilogue ----
    __syncthreads();                       // no VMEM outstanding; cheap
    float* sm = (float*)&WB[0][0];         // [32][68] = 8.7 KB < 32 KB
#pragma unroll
    for (int j = 0; j < 4; ++j) {
        const int row_l = rg * 16 + fq * 4 + j;
        sm[row_l * 68 + cg * 32 +  0 + fr] = accT0[j];
        sm[row_l * 68 + cg * 32 + 16 + fr] = accT1[j];
    }
    __syncthreads();
    if (w >= 2) return;                    // no barriers after this point

    // allowed-expert bitmask (uniform; scalar-cached)
    unsigned long long mbits = 0;
    for (int t = 0; t < nids; ++t) {
        const int e = ids[t];
        if (e >= 0 && e < E_NUM) mbits |= (1ull << e);
    }

    float* o_log = out;
    float* o_rw  = out + (size_t)T_ROWS * E_NUM;
    float* o_se  = o_rw + (size_t)T_ROWS * TOPK;

#pragma unroll
    for (int j = 0; j < 4; ++j) {
        const int row_l = w * 16 + fq * 4 + j;
        const int grow  = rb + row_l;
        float a0 = sm[row_l * 68 +  0 + fr];
        float a1 = sm[row_l * 68 + 16 + fr];
        float a2 = sm[row_l * 68 + 32 + fr];
        float a3 = sm[row_l * 68 + 48 + fr];
        float mv0 = ((mbits >> ( 0 + fr)) & 1) ? a0 : -10000.0f;
        float mv1 = ((mbits >> (16 + fr)) & 1) ? a1 : -10000.0f;
        float mv2 = ((mbits >> (32 + fr)) & 1) ? a2 : -10000.0f;
        float mv3 = ((mbits >> (48 + fr)) & 1) ? a3 : -10000.0f;
        o_log[(size_t)grow * 64 +  0 + fr] = mv0;
        o_log[(size_t)grow * 64 + 16 + fr] = mv1;
        o_log[(size_t)grow * 64 + 32 + fr] = mv2;
        o_log[(size_t)grow * 64 + 48 + fr] = mv3;

        float m = fmaxf(fmaxf(mv0, mv1), fmaxf(mv2, mv3));
#pragma unroll
        for (int off = 1; off < 16; off <<= 1) m = fmaxf(m, __shfl_xor(m, off));

        float tsum = 0.f, myv = 0.f;
        int   mye  = 0;
#pragma unroll
        for (int t = 0; t < TOPK; ++t) {
            float bv = mv0; int be = fr;
            if (mv1 > bv) { bv = mv1; be = 16 + fr; }
            if (mv2 > bv) { bv = mv2; be = 32 + fr; }
            if (mv3 > bv) { bv = mv3; be = 48 + fr; }
#pragma unroll
            for (int off = 1; off < 16; off <<= 1) {
                float ov = __shfl_xor(bv, off);
                int   oe = __shfl_xor(be, off);
                if (ov > bv || (ov == bv && oe < be)) { bv = ov; be = oe; }
            }
            const float pv = expf(bv - m);
            tsum += pv;
            if (fr == t) { myv = pv; mye = be; }
            if ((be & 15) == fr) {       // owner lane excludes winner
                const int bn = be >> 4;
                if      (bn == 0) mv0 = -3.4e38f;
                else if (bn == 1) mv1 = -3.4e38f;
                else if (bn == 2) mv2 = -3.4e38f;
                else              mv3 = -3.4e38f;
            }
        }
        if (fr < TOPK) {
            o_rw[(size_t)grow * TOPK + fr] = myv / tsum;
            o_se[(size_t)grow * TOPK + fr] = (float)mye;
        }
    }
}

extern "C" void kernel_launch(void* const* d_in, const int* in_sizes, int n_in,
                              void* d_out, int out_size, void* d_ws, size_t ws_size,
                              hipStream_t stream) {
    const float* X   = (const float*)d_in[0];
    const float* W   = (const float*)d_in[1];
    const int*   ids = (const int*)d_in[2];
    const int    nids = in_sizes[2];
    float* out = (float*)d_out;

    unsigned short* WS = (unsigned short*)d_ws;   // 1 MB swizzled W image

    hipLaunchKernelGGL(prep_w, dim3(NCH * WIMG / 16 / 256), dim3(256), 0, stream, W, WS);
    hipLaunchKernelGGL(router_main, dim3(T_ROWS / MROWS), dim3(256), 0, stream,
                       X, WS, ids, nids, out);
}